// Round 2
// baseline (634.686 us; speedup 1.0000x reference)
//
#include <hip/hip_runtime.h>
#include <hip/hip_bf16.h>
#include <stdint.h>

#define BB 512
#define HH 1024
#define NN 16384
#define MM 128
#define RR 4

typedef short short8 __attribute__((ext_vector_type(8)));
typedef float floatx4 __attribute__((ext_vector_type(4)));

__device__ __forceinline__ unsigned short f2bf(float f) {
  unsigned int u = __float_as_uint(f);
  unsigned int r = (u + 0x7fffu + ((u >> 16) & 1u)) >> 16;
  return (unsigned short)r;
}

__device__ __forceinline__ float bf2f(unsigned short u) {
  return __uint_as_float(((unsigned int)u) << 16);
}

__device__ __forceinline__ floatx4 mfma16(short8 a, short8 b, floatx4 c) {
  return __builtin_amdgcn_mfma_f32_16x16x32_bf16(a, b, c, 0, 0, 0);
}

// ---------------- K1: fused controller projection GEMM ----------------
// raw[b][r] = sum_k h[b][k] * W[r][k], rows: 0-127 key, 128-255 erase,
// 256-383 add, 384 beta, 385 gate, 386-388 shift. split-K (z=2) via atomics.
__global__ __launch_bounds__(256) void k1_proj(
    const float* __restrict__ h, const float* __restrict__ key_w,
    const float* __restrict__ erase_w, const float* __restrict__ add_w,
    const float* __restrict__ beta_w, const float* __restrict__ gate_w,
    const float* __restrict__ shift_w, float* __restrict__ raw) {
  __shared__ float hsT[32][34];
  __shared__ float wsT[32][34];
  const int t = threadIdx.x;
  const int b0 = blockIdx.x * 32;
  const int r0 = blockIdx.y * 32;
  const int kb = blockIdx.z * 512;
  const int tb = t & 15, tr = t >> 4;
  float acc00 = 0.f, acc01 = 0.f, acc10 = 0.f, acc11 = 0.f;
  for (int ko = 0; ko < 16; ++ko) {
    int kc = kb + ko * 32;
    __syncthreads();
    #pragma unroll
    for (int p = 0; p < 4; ++p) {
      int idx = t + p * 256;
      int col = idx & 31, row = idx >> 5;
      hsT[col][row] = h[(b0 + row) * HH + kc + col];
      int rg = r0 + row;
      float wv = 0.f;
      if (rg < 128)       wv = key_w[rg * HH + kc + col];
      else if (rg < 256)  wv = erase_w[(rg - 128) * HH + kc + col];
      else if (rg < 384)  wv = add_w[(rg - 256) * HH + kc + col];
      else if (rg == 384) wv = beta_w[kc + col];
      else if (rg == 385) wv = gate_w[kc + col];
      else if (rg < 389)  wv = shift_w[(rg - 386) * HH + kc + col];
      wsT[col][row] = wv;
    }
    __syncthreads();
    #pragma unroll
    for (int kk = 0; kk < 32; ++kk) {
      float a0 = hsT[kk][2 * tb], a1 = hsT[kk][2 * tb + 1];
      float w0 = wsT[kk][2 * tr], w1 = wsT[kk][2 * tr + 1];
      acc00 += a0 * w0; acc01 += a0 * w1;
      acc10 += a1 * w0; acc11 += a1 * w1;
    }
  }
  int bA = b0 + 2 * tb, bB = bA + 1;
  int rA = r0 + 2 * tr, rB = rA + 1;
  if (rA < 389) {
    unsafeAtomicAdd(&raw[bA * 392 + rA], acc00);
    unsafeAtomicAdd(&raw[bB * 392 + rA], acc10);
  }
  if (rB < 389) {
    unsafeAtomicAdd(&raw[bA * 392 + rB], acc01);
    unsafeAtomicAdd(&raw[bB * 392 + rB], acc11);
  }
}

// ---------------- K2: bias + activations + k-norm + s-softmax ----------------
__global__ __launch_bounds__(128) void k2_final(
    const float* __restrict__ raw, const float* __restrict__ key_b,
    const float* __restrict__ erase_b, const float* __restrict__ add_b,
    const float* __restrict__ beta_b, const float* __restrict__ gate_b,
    const float* __restrict__ shift_b,
    unsigned short* __restrict__ kbf, unsigned short* __restrict__ ebfT,
    unsigned short* __restrict__ abfT, float* __restrict__ beta,
    float* __restrict__ g, float* __restrict__ s3, float* __restrict__ knorm) {
  __shared__ float red[128];
  const int b = blockIdx.x, t = threadIdx.x;
  const float* rb = raw + b * 392;
  float kv = fminf(fmaxf(rb[t] + key_b[t], 0.f), 1.f);
  kbf[b * MM + t] = f2bf(kv);
  float ev = fminf(fmaxf(rb[128 + t] + erase_b[t], 0.f), 1.f);
  ebfT[t * BB + b] = f2bf(ev);
  float av = fminf(fmaxf(rb[256 + t] + add_b[t], 0.f), 1.f);
  abfT[t * BB + b] = f2bf(av);
  red[t] = kv * kv;
  __syncthreads();
  for (int off = 64; off >= 1; off >>= 1) {
    if (t < off) red[t] += red[t + off];
    __syncthreads();
  }
  if (t == 0) {
    knorm[b] = sqrtf(red[0]);
    beta[b] = fmaxf(rb[384] + beta_b[0], 0.f);
    g[b] = fminf(fmaxf(rb[385] + gate_b[0], 0.f), 1.f);
    float x0 = rb[386] + shift_b[0];
    float x1 = rb[387] + shift_b[1];
    float x2 = rb[388] + shift_b[2];
    float mx = fmaxf(x0, fmaxf(x1, x2));
    float e0 = __expf(x0 - mx), e1 = __expf(x1 - mx), e2 = __expf(x2 - mx);
    float inv = 1.f / (e0 + e1 + e2);
    s3[b * 3 + 0] = e0 * inv; s3[b * 3 + 1] = e1 * inv; s3[b * 3 + 2] = e2 * inv;
  }
}

// ---------------- K3: m row norms + m_bf16 + m_bf16^T (single m read) ----------------
__global__ __launch_bounds__(256) void k3_mprep(
    const float* __restrict__ m, unsigned short* __restrict__ mbf,
    unsigned short* __restrict__ mbfT, float* __restrict__ mnorm) {
  __shared__ float ldsT[128][65];
  const int t = threadIdx.x;
  const int n0 = blockIdx.x * 64;
  const int lane = t & 63, w = t >> 6;
  for (int ri = 0; ri < 16; ++ri) {
    int nloc = w * 16 + ri;
    int n = n0 + nloc;
    float v0 = m[n * MM + lane];
    float v1 = m[n * MM + lane + 64];
    mbf[n * MM + lane] = f2bf(v0);
    mbf[n * MM + lane + 64] = f2bf(v1);
    ldsT[lane][nloc] = v0;
    ldsT[lane + 64][nloc] = v1;
    float sq = v0 * v0 + v1 * v1;
    #pragma unroll
    for (int off = 32; off >= 1; off >>= 1) sq += __shfl_xor(sq, off, 64);
    if (lane == 0) mnorm[n] = sqrtf(sq);
  }
  __syncthreads();
  for (int q = 0; q < 32; ++q) {
    int mc = q * 4 + (t >> 6);
    int nloc = t & 63;
    mbfT[mc * NN + n0 + nloc] = f2bf(ldsT[mc][nloc]);
  }
}

// ---------------- K4: sim GEMM + fused exp (max=1 bound) + atomic rowsum ----
// cosine sim is bounded by ~1, so softmax can shift by 1.0 instead of rowmax:
// p = exp(beta*(sim-1)) stored bf16; rowsum accumulated via atomics.
__global__ __launch_bounds__(256) void k4_sim(
    const unsigned short* __restrict__ kbf, const unsigned short* __restrict__ mbf,
    const float* __restrict__ knorm, const float* __restrict__ mnorm,
    const float* __restrict__ beta, unsigned short* __restrict__ p,
    float* __restrict__ rowsum) {
  const int t = threadIdx.x;
  const int lane = t & 63, w = t >> 6;
  const int n0 = blockIdx.x * 64;
  const int b0 = blockIdx.y * 64 + w * 16;
  const int lm = lane & 15, quad = lane >> 4;
  floatx4 acc[4];
  #pragma unroll
  for (int i = 0; i < 4; ++i) acc[i] = (floatx4){0.f, 0.f, 0.f, 0.f};
  #pragma unroll
  for (int s = 0; s < 4; ++s) {
    short8 avf = *(const short8*)(kbf + (b0 + lm) * MM + s * 32 + quad * 8);
    #pragma unroll
    for (int nt = 0; nt < 4; ++nt) {
      short8 bvf = *(const short8*)(mbf + (n0 + nt * 16 + lm) * MM + s * 32 + quad * 8);
      acc[nt] = mfma16(avf, bvf, acc[nt]);
    }
  }
  float bt[4], kn[4], psum[4];
  #pragma unroll
  for (int r = 0; r < 4; ++r) {
    int b = b0 + quad * 4 + r;
    bt[r] = beta[b];
    kn[r] = knorm[b];
    psum[r] = 0.f;
  }
  #pragma unroll
  for (int nt = 0; nt < 4; ++nt) {
    int n = n0 + nt * 16 + lm;
    float mn = mnorm[n];
    #pragma unroll
    for (int r = 0; r < 4; ++r) {
      int b = b0 + quad * 4 + r;
      float val = acc[nt][r] / (kn[r] * mn + 1e-6f);
      float pe = __expf(bt[r] * (val - 1.f));
      p[(size_t)b * NN + n] = f2bf(pe);
      psum[r] += pe;
    }
  }
  #pragma unroll
  for (int r = 0; r < 4; ++r) {
    float s = psum[r];
    s += __shfl_xor(s, 1, 64);
    s += __shfl_xor(s, 2, 64);
    s += __shfl_xor(s, 4, 64);
    s += __shfl_xor(s, 8, 64);
    if (lm == 0) unsafeAtomicAdd(&rowsum[b0 + quad * 4 + r], s);
  }
}

// ---------------- KC: fused gate + 3-tap circular conv for 5 heads ----------------
__global__ __launch_bounds__(256) void kc_update(
    const unsigned short* __restrict__ p, const float* __restrict__ ww,
    const float* __restrict__ wr, const float* __restrict__ gv,
    const float* __restrict__ s3, const float* __restrict__ rowsum,
    float* __restrict__ out_ww, float* __restrict__ out_wr) {
  __shared__ float wg[5][264];
  const int b = blockIdx.x, t = threadIdx.x;
  const int chunk0 = blockIdx.y * 2048;
  const float g = gv[b];
  const float invZ = 1.f / rowsum[b];
  const float s0 = s3[b * 3], s1 = s3[b * 3 + 1], s2 = s3[b * 3 + 2];
  const float om = 1.f - g;
  const float* pv[5];
  float* po[5];
  pv[0] = ww + (size_t)b * NN;
  po[0] = out_ww + (size_t)b * NN;
  #pragma unroll
  for (int h = 1; h < 5; ++h) {
    pv[h] = wr + ((size_t)(h - 1) * BB + b) * NN;
    po[h] = out_wr + ((size_t)(h - 1) * BB + b) * NN;
  }
  for (int it = 0; it < 8; ++it) {
    int nbase = chunk0 + it * 256;
    int n = nbase + t;
    float wcv = bf2f(p[(size_t)b * NN + n]) * invZ;
    #pragma unroll
    for (int h = 0; h < 5; ++h) wg[h][t + 1] = g * wcv + om * pv[h][n];
    if (t < 2) {
      int hn = (t == 0) ? ((nbase - 1) & (NN - 1)) : ((nbase + 256) & (NN - 1));
      int li = (t == 0) ? 0 : 257;
      float wch = bf2f(p[(size_t)b * NN + hn]) * invZ;
      #pragma unroll
      for (int h = 0; h < 5; ++h) wg[h][li] = g * wch + om * pv[h][hn];
    }
    __syncthreads();
    #pragma unroll
    for (int h = 0; h < 5; ++h) {
      float wt = s0 * wg[h][t + 2] + s1 * wg[h][t + 1] + s2 * wg[h][t];
      po[h][n] = wt;
    }
    __syncthreads();
  }
}

// ---------------- KD: m_t = m*(1 - ww^T e) + ww^T a ----------------
// reads ww fp32 directly (16 consecutive floats per quad-row = 64B segments,
// each element fetched once per block) — no separate transpose kernel needed.
__global__ __launch_bounds__(256) void kd_mem(
    const float* __restrict__ ww, const unsigned short* __restrict__ ebfT,
    const unsigned short* __restrict__ abfT, const float* __restrict__ m,
    float* __restrict__ out_m) {
  const int t = threadIdx.x;
  const int lane = t & 63, w = t >> 6;
  const int lm = lane & 15, quad = lane >> 4;
  const int nb = blockIdx.x * 64 + w * 16;
  const int n = nb + lm;
  floatx4 accE[8], accA[8];
  #pragma unroll
  for (int i = 0; i < 8; ++i) {
    accE[i] = (floatx4){0.f, 0.f, 0.f, 0.f};
    accA[i] = (floatx4){0.f, 0.f, 0.f, 0.f};
  }
  for (int s = 0; s < 16; ++s) {
    int k0 = s * 32 + quad * 8;
    const float* wp = ww + (size_t)k0 * NN + n;
    short8 av;
    #pragma unroll
    for (int j = 0; j < 8; ++j) av[j] = (short)f2bf(wp[(size_t)j * NN]);
    #pragma unroll
    for (int mt = 0; mt < 8; ++mt) {
      short8 evf = *(const short8*)(ebfT + (mt * 16 + lm) * BB + k0);
      short8 avf = *(const short8*)(abfT + (mt * 16 + lm) * BB + k0);
      accE[mt] = mfma16(av, evf, accE[mt]);
      accA[mt] = mfma16(av, avf, accA[mt]);
    }
  }
  #pragma unroll
  for (int mt = 0; mt < 8; ++mt) {
    int mc = mt * 16 + lm;
    #pragma unroll
    for (int r = 0; r < 4; ++r) {
      int nn = nb + quad * 4 + r;
      float mv = m[nn * MM + mc];
      out_m[nn * MM + mc] = mv * (1.f - accE[mt][r]) + accA[mt][r];
    }
  }
}

// ---------------- KE: r_t = einsum(wr, m) (bf16 MFMA, split-K=16 + atomics) ----------------
__global__ __launch_bounds__(256) void ke_read(
    const float* __restrict__ wr, const unsigned short* __restrict__ mbfT,
    float* __restrict__ out_r) {
  const int t = threadIdx.x;
  const int lane = t & 63, w = t >> 6;
  const int lm = lane & 15, quad = lane >> 4;
  const int rb0 = blockIdx.x * 64 + w * 16;
  const int kc0 = blockIdx.y * 1024;
  floatx4 acc[8];
  #pragma unroll
  for (int i = 0; i < 8; ++i) acc[i] = (floatx4){0.f, 0.f, 0.f, 0.f};
  for (int s = 0; s < 32; ++s) {
    int ns = kc0 + s * 32 + quad * 8;
    const float* ap = wr + (size_t)(rb0 + lm) * NN + ns;
    floatx4 f0 = *(const floatx4*)(ap);
    floatx4 f1 = *(const floatx4*)(ap + 4);
    short8 av;
    av[0] = (short)f2bf(f0[0]); av[1] = (short)f2bf(f0[1]);
    av[2] = (short)f2bf(f0[2]); av[3] = (short)f2bf(f0[3]);
    av[4] = (short)f2bf(f1[0]); av[5] = (short)f2bf(f1[1]);
    av[6] = (short)f2bf(f1[2]); av[7] = (short)f2bf(f1[3]);
    #pragma unroll
    for (int mt = 0; mt < 8; ++mt) {
      short8 bv = *(const short8*)(mbfT + (size_t)(mt * 16 + lm) * NN + ns);
      acc[mt] = mfma16(av, bv, acc[mt]);
    }
  }
  #pragma unroll
  for (int mt = 0; mt < 8; ++mt) {
    int mc = mt * 16 + lm;
    #pragma unroll
    for (int r = 0; r < 4; ++r) {
      int rb = rb0 + quad * 4 + r;
      int rr = rb >> 9, bb = rb & 511;
      unsafeAtomicAdd(&out_r[bb * (RR * MM) + rr * MM + mc], acc[mt][r]);
    }
  }
}

extern "C" void kernel_launch(void* const* d_in, const int* in_sizes, int n_in,
                              void* d_out, int out_size, void* d_ws, size_t ws_size,
                              hipStream_t stream) {
  const float* h_t    = (const float*)d_in[0];
  const float* wr     = (const float*)d_in[1];
  const float* ww     = (const float*)d_in[2];
  const float* m      = (const float*)d_in[3];
  const float* key_w  = (const float*)d_in[4];
  const float* key_b  = (const float*)d_in[5];
  const float* beta_w = (const float*)d_in[6];
  const float* beta_b = (const float*)d_in[7];
  const float* gate_w = (const float*)d_in[8];
  const float* gate_b = (const float*)d_in[9];
  const float* shift_w = (const float*)d_in[10];
  const float* shift_b = (const float*)d_in[11];
  const float* erase_w = (const float*)d_in[14];
  const float* erase_b = (const float*)d_in[15];
  const float* add_w   = (const float*)d_in[16];
  const float* add_b   = (const float*)d_in[17];

  char* wsb = (char*)d_ws;
  float* raw            = (float*)(wsb + 0);          // 512*392*4 = 802816
  float* rowsum         = (float*)(wsb + 802816);     // 2048 (memset with raw)
  unsigned short* kbf   = (unsigned short*)(wsb + 804864);   // 131072
  unsigned short* ebfT  = (unsigned short*)(wsb + 935936);   // 131072
  unsigned short* abfT  = (unsigned short*)(wsb + 1067008);  // 131072
  float* beta           = (float*)(wsb + 1198080);    // 2048
  float* g              = (float*)(wsb + 1200128);    // 2048
  float* s3             = (float*)(wsb + 1202176);    // 6144
  float* knorm          = (float*)(wsb + 1208320);    // 2048
  float* mnorm          = (float*)(wsb + 1210368);    // 65536
  unsigned short* mbf   = (unsigned short*)(wsb + 1275904);  // 4194304
  unsigned short* mbfT  = (unsigned short*)(wsb + 5470208);  // 4194304
  unsigned short* pbuf  = (unsigned short*)(wsb + 9664512);  // 16777216 (total ~26.4 MB)

  float* out_r  = (float*)d_out;                 // (B,R,M)  262144
  float* out_wr = (float*)d_out + 262144;        // (R,B,N)  33554432
  float* out_ww = (float*)d_out + 33816576;      // (B,N)    8388608
  float* out_m  = (float*)d_out + 42205184;      // (N,M)    2097152

  hipMemsetAsync(d_out, 0, 262144 * sizeof(float), stream);   // r_t accum
  hipMemsetAsync(raw, 0, 804864, stream);                     // raw + rowsum

  k1_proj<<<dim3(16, 13, 2), 256, 0, stream>>>(h_t, key_w, erase_w, add_w,
                                               beta_w, gate_w, shift_w, raw);
  k2_final<<<512, 128, 0, stream>>>(raw, key_b, erase_b, add_b, beta_b, gate_b,
                                    shift_b, kbf, ebfT, abfT, beta, g, s3, knorm);
  k3_mprep<<<256, 256, 0, stream>>>(m, mbf, mbfT, mnorm);
  k4_sim<<<dim3(256, 8), 256, 0, stream>>>(kbf, mbf, knorm, mnorm, beta, pbuf, rowsum);
  kc_update<<<dim3(512, 8), 256, 0, stream>>>(pbuf, ww, wr, g, s3, rowsum,
                                              out_ww, out_wr);
  kd_mem<<<256, 256, 0, stream>>>(ww, ebfT, abfT, m, out_m);
  ke_read<<<dim3(32, 16), 256, 0, stream>>>(wr, mbfT, out_r);
}

// Round 3
// 605.558 us; speedup vs baseline: 1.0481x; 1.0481x over previous
//
#include <hip/hip_runtime.h>
#include <hip/hip_bf16.h>
#include <stdint.h>

#define BB 512
#define HH 1024
#define NN 16384
#define MM 128
#define RR 4

typedef short short8 __attribute__((ext_vector_type(8)));
typedef float floatx4 __attribute__((ext_vector_type(4)));

__device__ __forceinline__ unsigned short f2bf(float f) {
  unsigned int u = __float_as_uint(f);
  unsigned int r = (u + 0x7fffu + ((u >> 16) & 1u)) >> 16;
  return (unsigned short)r;
}

__device__ __forceinline__ float bf2f(unsigned short u) {
  return __uint_as_float(((unsigned int)u) << 16);
}

__device__ __forceinline__ floatx4 mfma16(short8 a, short8 b, floatx4 c) {
  return __builtin_amdgcn_mfma_f32_16x16x32_bf16(a, b, c, 0, 0, 0);
}

// ---------------- K1: fused controller projection GEMM ----------------
// raw[b][r] = sum_k h[b][k] * W[r][k], rows: 0-127 key, 128-255 erase,
// 256-383 add, 384 beta, 385 gate, 386-388 shift. split-K (z=2) via atomics.
__global__ __launch_bounds__(256) void k1_proj(
    const float* __restrict__ h, const float* __restrict__ key_w,
    const float* __restrict__ erase_w, const float* __restrict__ add_w,
    const float* __restrict__ beta_w, const float* __restrict__ gate_w,
    const float* __restrict__ shift_w, float* __restrict__ raw) {
  __shared__ float hsT[32][34];
  __shared__ float wsT[32][34];
  const int t = threadIdx.x;
  const int b0 = blockIdx.x * 32;
  const int r0 = blockIdx.y * 32;
  const int kb = blockIdx.z * 512;
  const int tb = t & 15, tr = t >> 4;
  float acc00 = 0.f, acc01 = 0.f, acc10 = 0.f, acc11 = 0.f;
  for (int ko = 0; ko < 16; ++ko) {
    int kc = kb + ko * 32;
    __syncthreads();
    #pragma unroll
    for (int p = 0; p < 4; ++p) {
      int idx = t + p * 256;
      int col = idx & 31, row = idx >> 5;
      hsT[col][row] = h[(b0 + row) * HH + kc + col];
      int rg = r0 + row;
      float wv = 0.f;
      if (rg < 128)       wv = key_w[rg * HH + kc + col];
      else if (rg < 256)  wv = erase_w[(rg - 128) * HH + kc + col];
      else if (rg < 384)  wv = add_w[(rg - 256) * HH + kc + col];
      else if (rg == 384) wv = beta_w[kc + col];
      else if (rg == 385) wv = gate_w[kc + col];
      else if (rg < 389)  wv = shift_w[(rg - 386) * HH + kc + col];
      wsT[col][row] = wv;
    }
    __syncthreads();
    #pragma unroll
    for (int kk = 0; kk < 32; ++kk) {
      float a0 = hsT[kk][2 * tb], a1 = hsT[kk][2 * tb + 1];
      float w0 = wsT[kk][2 * tr], w1 = wsT[kk][2 * tr + 1];
      acc00 += a0 * w0; acc01 += a0 * w1;
      acc10 += a1 * w0; acc11 += a1 * w1;
    }
  }
  int bA = b0 + 2 * tb, bB = bA + 1;
  int rA = r0 + 2 * tr, rB = rA + 1;
  if (rA < 389) {
    unsafeAtomicAdd(&raw[bA * 392 + rA], acc00);
    unsafeAtomicAdd(&raw[bB * 392 + rA], acc10);
  }
  if (rB < 389) {
    unsafeAtomicAdd(&raw[bA * 392 + rB], acc01);
    unsafeAtomicAdd(&raw[bB * 392 + rB], acc11);
  }
}

// ---------------- K2: bias + activations + k-norm + s-softmax ----------------
__global__ __launch_bounds__(128) void k2_final(
    const float* __restrict__ raw, const float* __restrict__ key_b,
    const float* __restrict__ erase_b, const float* __restrict__ add_b,
    const float* __restrict__ beta_b, const float* __restrict__ gate_b,
    const float* __restrict__ shift_b,
    unsigned short* __restrict__ kbf, unsigned short* __restrict__ ebfT,
    unsigned short* __restrict__ abfT, float* __restrict__ beta,
    float* __restrict__ g, float* __restrict__ s3, float* __restrict__ knorm) {
  __shared__ float red[128];
  const int b = blockIdx.x, t = threadIdx.x;
  const float* rb = raw + b * 392;
  float kv = fminf(fmaxf(rb[t] + key_b[t], 0.f), 1.f);
  kbf[b * MM + t] = f2bf(kv);
  float ev = fminf(fmaxf(rb[128 + t] + erase_b[t], 0.f), 1.f);
  ebfT[t * BB + b] = f2bf(ev);
  float av = fminf(fmaxf(rb[256 + t] + add_b[t], 0.f), 1.f);
  abfT[t * BB + b] = f2bf(av);
  red[t] = kv * kv;
  __syncthreads();
  for (int off = 64; off >= 1; off >>= 1) {
    if (t < off) red[t] += red[t + off];
    __syncthreads();
  }
  if (t == 0) {
    knorm[b] = sqrtf(red[0]);
    beta[b] = fmaxf(rb[384] + beta_b[0], 0.f);
    g[b] = fminf(fmaxf(rb[385] + gate_b[0], 0.f), 1.f);
    float x0 = rb[386] + shift_b[0];
    float x1 = rb[387] + shift_b[1];
    float x2 = rb[388] + shift_b[2];
    float mx = fmaxf(x0, fmaxf(x1, x2));
    float e0 = __expf(x0 - mx), e1 = __expf(x1 - mx), e2 = __expf(x2 - mx);
    float inv = 1.f / (e0 + e1 + e2);
    s3[b * 3 + 0] = e0 * inv; s3[b * 3 + 1] = e1 * inv; s3[b * 3 + 2] = e2 * inv;
  }
}

// ---------------- K3: m row norms + m_bf16 + m_bf16^T (single m read) ----------------
__global__ __launch_bounds__(256) void k3_mprep(
    const float* __restrict__ m, unsigned short* __restrict__ mbf,
    unsigned short* __restrict__ mbfT, float* __restrict__ mnorm) {
  __shared__ float ldsT[128][65];
  const int t = threadIdx.x;
  const int n0 = blockIdx.x * 64;
  const int lane = t & 63, w = t >> 6;
  for (int ri = 0; ri < 16; ++ri) {
    int nloc = w * 16 + ri;
    int n = n0 + nloc;
    float v0 = m[n * MM + lane];
    float v1 = m[n * MM + lane + 64];
    mbf[n * MM + lane] = f2bf(v0);
    mbf[n * MM + lane + 64] = f2bf(v1);
    ldsT[lane][nloc] = v0;
    ldsT[lane + 64][nloc] = v1;
    float sq = v0 * v0 + v1 * v1;
    #pragma unroll
    for (int off = 32; off >= 1; off >>= 1) sq += __shfl_xor(sq, off, 64);
    if (lane == 0) mnorm[n] = sqrtf(sq);
  }
  __syncthreads();
  for (int q = 0; q < 32; ++q) {
    int mc = q * 4 + (t >> 6);
    int nloc = t & 63;
    mbfT[mc * NN + n0 + nloc] = f2bf(ldsT[mc][nloc]);
  }
}

// ---------------- K4: sim GEMM + fused exp (max=1 bound) + atomic rowsum ----
// cosine sim is bounded by ~1, so softmax can shift by 1.0 instead of rowmax:
// p = exp(beta*(sim-1)) stored bf16; rowsum accumulated via atomics.
__global__ __launch_bounds__(256) void k4_sim(
    const unsigned short* __restrict__ kbf, const unsigned short* __restrict__ mbf,
    const float* __restrict__ knorm, const float* __restrict__ mnorm,
    const float* __restrict__ beta, unsigned short* __restrict__ p,
    float* __restrict__ rowsum) {
  const int t = threadIdx.x;
  const int lane = t & 63, w = t >> 6;
  const int n0 = blockIdx.x * 64;
  const int b0 = blockIdx.y * 64 + w * 16;
  const int lm = lane & 15, quad = lane >> 4;
  floatx4 acc[4];
  #pragma unroll
  for (int i = 0; i < 4; ++i) acc[i] = (floatx4){0.f, 0.f, 0.f, 0.f};
  #pragma unroll
  for (int s = 0; s < 4; ++s) {
    short8 avf = *(const short8*)(kbf + (b0 + lm) * MM + s * 32 + quad * 8);
    #pragma unroll
    for (int nt = 0; nt < 4; ++nt) {
      short8 bvf = *(const short8*)(mbf + (n0 + nt * 16 + lm) * MM + s * 32 + quad * 8);
      acc[nt] = mfma16(avf, bvf, acc[nt]);
    }
  }
  float bt[4], kn[4], psum[4];
  #pragma unroll
  for (int r = 0; r < 4; ++r) {
    int b = b0 + quad * 4 + r;
    bt[r] = beta[b];
    kn[r] = knorm[b];
    psum[r] = 0.f;
  }
  #pragma unroll
  for (int nt = 0; nt < 4; ++nt) {
    int n = n0 + nt * 16 + lm;
    float mn = mnorm[n];
    #pragma unroll
    for (int r = 0; r < 4; ++r) {
      int b = b0 + quad * 4 + r;
      float val = acc[nt][r] / (kn[r] * mn + 1e-6f);
      float pe = __expf(bt[r] * (val - 1.f));
      p[(size_t)b * NN + n] = f2bf(pe);
      psum[r] += pe;
    }
  }
  #pragma unroll
  for (int r = 0; r < 4; ++r) {
    float s = psum[r];
    s += __shfl_xor(s, 1, 64);
    s += __shfl_xor(s, 2, 64);
    s += __shfl_xor(s, 4, 64);
    s += __shfl_xor(s, 8, 64);
    if (lm == 0) unsafeAtomicAdd(&rowsum[b0 + quad * 4 + r], s);
  }
}

// ---------------- KT: ww (B,N) -> ww^T bf16 (N,B) ----------------
__global__ __launch_bounds__(256) void kt_wwT(
    const float* __restrict__ ww, unsigned short* __restrict__ wwT) {
  __shared__ float lds[64][65];
  const int t = threadIdx.x;
  const int n0 = blockIdx.x * 64, b0 = blockIdx.y * 64;
  const int c = t & 63, r = t >> 6;
  #pragma unroll
  for (int p = 0; p < 16; ++p)
    lds[r + 4 * p][c] = ww[(size_t)(b0 + r + 4 * p) * NN + n0 + c];
  __syncthreads();
  #pragma unroll
  for (int q = 0; q < 16; ++q) {
    int nr = r + 4 * q;
    wwT[(size_t)(n0 + nr) * BB + b0 + c] = f2bf(lds[c][nr]);
  }
}

// ---------------- KC: fused gate + 3-tap circular conv for 5 heads ----------------
__global__ __launch_bounds__(256) void kc_update(
    const unsigned short* __restrict__ p, const float* __restrict__ ww,
    const float* __restrict__ wr, const float* __restrict__ gv,
    const float* __restrict__ s3, const float* __restrict__ rowsum,
    float* __restrict__ out_ww, float* __restrict__ out_wr) {
  __shared__ float wg[5][264];
  const int b = blockIdx.x, t = threadIdx.x;
  const int chunk0 = blockIdx.y * 2048;
  const float g = gv[b];
  const float invZ = 1.f / rowsum[b];
  const float s0 = s3[b * 3], s1 = s3[b * 3 + 1], s2 = s3[b * 3 + 2];
  const float om = 1.f - g;
  const float* pv[5];
  float* po[5];
  pv[0] = ww + (size_t)b * NN;
  po[0] = out_ww + (size_t)b * NN;
  #pragma unroll
  for (int h = 1; h < 5; ++h) {
    pv[h] = wr + ((size_t)(h - 1) * BB + b) * NN;
    po[h] = out_wr + ((size_t)(h - 1) * BB + b) * NN;
  }
  for (int it = 0; it < 8; ++it) {
    int nbase = chunk0 + it * 256;
    int n = nbase + t;
    float wcv = bf2f(p[(size_t)b * NN + n]) * invZ;
    #pragma unroll
    for (int h = 0; h < 5; ++h) wg[h][t + 1] = g * wcv + om * pv[h][n];
    if (t < 2) {
      int hn = (t == 0) ? ((nbase - 1) & (NN - 1)) : ((nbase + 256) & (NN - 1));
      int li = (t == 0) ? 0 : 257;
      float wch = bf2f(p[(size_t)b * NN + hn]) * invZ;
      #pragma unroll
      for (int h = 0; h < 5; ++h) wg[h][li] = g * wch + om * pv[h][hn];
    }
    __syncthreads();
    #pragma unroll
    for (int h = 0; h < 5; ++h) {
      float wt = s0 * wg[h][t + 2] + s1 * wg[h][t + 1] + s2 * wg[h][t];
      po[h][n] = wt;
    }
    __syncthreads();
  }
}

// ---------------- KD: m_t = m*(1 - ww^T e) + ww^T a (bf16 MFMA, K=512) ----------------
__global__ __launch_bounds__(256) void kd_mem(
    const unsigned short* __restrict__ wwT, const unsigned short* __restrict__ ebfT,
    const unsigned short* __restrict__ abfT, const float* __restrict__ m,
    float* __restrict__ out_m) {
  const int t = threadIdx.x;
  const int lane = t & 63, w = t >> 6;
  const int lm = lane & 15, quad = lane >> 4;
  const int nb = blockIdx.x * 64 + w * 16;
  floatx4 accE[8], accA[8];
  #pragma unroll
  for (int i = 0; i < 8; ++i) {
    accE[i] = (floatx4){0.f, 0.f, 0.f, 0.f};
    accA[i] = (floatx4){0.f, 0.f, 0.f, 0.f};
  }
  for (int s = 0; s < 16; ++s) {
    short8 av = *(const short8*)(wwT + (size_t)(nb + lm) * BB + s * 32 + quad * 8);
    #pragma unroll
    for (int mt = 0; mt < 8; ++mt) {
      short8 evf = *(const short8*)(ebfT + (mt * 16 + lm) * BB + s * 32 + quad * 8);
      short8 avf = *(const short8*)(abfT + (mt * 16 + lm) * BB + s * 32 + quad * 8);
      accE[mt] = mfma16(av, evf, accE[mt]);
      accA[mt] = mfma16(av, avf, accA[mt]);
    }
  }
  #pragma unroll
  for (int mt = 0; mt < 8; ++mt) {
    int mc = mt * 16 + lm;
    #pragma unroll
    for (int r = 0; r < 4; ++r) {
      int n = nb + quad * 4 + r;
      float mv = m[n * MM + mc];
      out_m[n * MM + mc] = mv * (1.f - accE[mt][r]) + accA[mt][r];
    }
  }
}

// ---------------- KE: r_t = einsum(wr, m) (bf16 MFMA, split-K=16 + atomics) ----------------
__global__ __launch_bounds__(256) void ke_read(
    const float* __restrict__ wr, const unsigned short* __restrict__ mbfT,
    float* __restrict__ out_r) {
  const int t = threadIdx.x;
  const int lane = t & 63, w = t >> 6;
  const int lm = lane & 15, quad = lane >> 4;
  const int rb0 = blockIdx.x * 64 + w * 16;
  const int kc0 = blockIdx.y * 1024;
  floatx4 acc[8];
  #pragma unroll
  for (int i = 0; i < 8; ++i) acc[i] = (floatx4){0.f, 0.f, 0.f, 0.f};
  for (int s = 0; s < 32; ++s) {
    int ns = kc0 + s * 32 + quad * 8;
    const float* ap = wr + (size_t)(rb0 + lm) * NN + ns;
    floatx4 f0 = *(const floatx4*)(ap);
    floatx4 f1 = *(const floatx4*)(ap + 4);
    short8 av;
    av[0] = (short)f2bf(f0[0]); av[1] = (short)f2bf(f0[1]);
    av[2] = (short)f2bf(f0[2]); av[3] = (short)f2bf(f0[3]);
    av[4] = (short)f2bf(f1[0]); av[5] = (short)f2bf(f1[1]);
    av[6] = (short)f2bf(f1[2]); av[7] = (short)f2bf(f1[3]);
    #pragma unroll
    for (int mt = 0; mt < 8; ++mt) {
      short8 bv = *(const short8*)(mbfT + (size_t)(mt * 16 + lm) * NN + ns);
      acc[mt] = mfma16(av, bv, acc[mt]);
    }
  }
  #pragma unroll
  for (int mt = 0; mt < 8; ++mt) {
    int mc = mt * 16 + lm;
    #pragma unroll
    for (int r = 0; r < 4; ++r) {
      int rb = rb0 + quad * 4 + r;
      int rr = rb >> 9, bb = rb & 511;
      unsafeAtomicAdd(&out_r[bb * (RR * MM) + rr * MM + mc], acc[mt][r]);
    }
  }
}

extern "C" void kernel_launch(void* const* d_in, const int* in_sizes, int n_in,
                              void* d_out, int out_size, void* d_ws, size_t ws_size,
                              hipStream_t stream) {
  const float* h_t    = (const float*)d_in[0];
  const float* wr     = (const float*)d_in[1];
  const float* ww     = (const float*)d_in[2];
  const float* m      = (const float*)d_in[3];
  const float* key_w  = (const float*)d_in[4];
  const float* key_b  = (const float*)d_in[5];
  const float* beta_w = (const float*)d_in[6];
  const float* beta_b = (const float*)d_in[7];
  const float* gate_w = (const float*)d_in[8];
  const float* gate_b = (const float*)d_in[9];
  const float* shift_w = (const float*)d_in[10];
  const float* shift_b = (const float*)d_in[11];
  const float* erase_w = (const float*)d_in[14];
  const float* erase_b = (const float*)d_in[15];
  const float* add_w   = (const float*)d_in[16];
  const float* add_b   = (const float*)d_in[17];

  char* wsb = (char*)d_ws;
  float* raw            = (float*)(wsb + 0);          // 512*392*4 = 802816
  float* rowsum         = (float*)(wsb + 802816);     // 2048 (memset with raw)
  unsigned short* kbf   = (unsigned short*)(wsb + 804864);   // 131072
  unsigned short* ebfT  = (unsigned short*)(wsb + 935936);   // 131072
  unsigned short* abfT  = (unsigned short*)(wsb + 1067008);  // 131072
  float* beta           = (float*)(wsb + 1198080);    // 2048
  float* g              = (float*)(wsb + 1200128);    // 2048
  float* s3             = (float*)(wsb + 1202176);    // 6144
  float* knorm          = (float*)(wsb + 1208320);    // 2048
  float* mnorm          = (float*)(wsb + 1210368);    // 65536
  unsigned short* mbf   = (unsigned short*)(wsb + 1275904);  // 4194304
  unsigned short* mbfT  = (unsigned short*)(wsb + 5470208);  // 4194304
  unsigned short* pbuf  = (unsigned short*)(wsb + 9664512);  // 16777216
  unsigned short* wwT   = (unsigned short*)(wsb + 26441728); // 16777216 (total ~43.2 MB)

  float* out_r  = (float*)d_out;                 // (B,R,M)  262144
  float* out_wr = (float*)d_out + 262144;        // (R,B,N)  33554432
  float* out_ww = (float*)d_out + 33816576;      // (B,N)    8388608
  float* out_m  = (float*)d_out + 42205184;      // (N,M)    2097152

  hipMemsetAsync(d_out, 0, 262144 * sizeof(float), stream);   // r_t accum
  hipMemsetAsync(raw, 0, 804864, stream);                     // raw + rowsum

  k1_proj<<<dim3(16, 13, 2), 256, 0, stream>>>(h_t, key_w, erase_w, add_w,
                                               beta_w, gate_w, shift_w, raw);
  k2_final<<<512, 128, 0, stream>>>(raw, key_b, erase_b, add_b, beta_b, gate_b,
                                    shift_b, kbf, ebfT, abfT, beta, g, s3, knorm);
  k3_mprep<<<256, 256, 0, stream>>>(m, mbf, mbfT, mnorm);
  k4_sim<<<dim3(256, 8), 256, 0, stream>>>(kbf, mbf, knorm, mnorm, beta, pbuf, rowsum);
  kt_wwT<<<dim3(256, 8), 256, 0, stream>>>(ww, wwT);
  kc_update<<<dim3(512, 8), 256, 0, stream>>>(pbuf, ww, wr, g, s3, rowsum,
                                              out_ww, out_wr);
  kd_mem<<<256, 256, 0, stream>>>(wwT, ebfT, abfT, m, out_m);
  ke_read<<<dim3(32, 16), 256, 0, stream>>>(wr, mbfT, out_r);
}

// Round 4
// 597.147 us; speedup vs baseline: 1.0629x; 1.0141x over previous
//
#include <hip/hip_runtime.h>
#include <hip/hip_bf16.h>
#include <stdint.h>

#define BB 512
#define HH 1024
#define NN 16384
#define MM 128
#define RR 4

typedef short short8 __attribute__((ext_vector_type(8)));
typedef float floatx4 __attribute__((ext_vector_type(4)));

__device__ __forceinline__ unsigned short f2bf(float f) {
  unsigned int u = __float_as_uint(f);
  unsigned int r = (u + 0x7fffu + ((u >> 16) & 1u)) >> 16;
  return (unsigned short)r;
}

__device__ __forceinline__ float bf2f(unsigned short u) {
  return __uint_as_float(((unsigned int)u) << 16);
}

__device__ __forceinline__ floatx4 mfma16(short8 a, short8 b, floatx4 c) {
  return __builtin_amdgcn_mfma_f32_16x16x32_bf16(a, b, c, 0, 0, 0);
}

// ---------------- K1: fused controller projection GEMM ----------------
// raw[b][r] = sum_k h[b][k] * W[r][k], rows: 0-127 key, 128-255 erase,
// 256-383 add, 384 beta, 385 gate, 386-388 shift. split-K (z=2) via atomics.
__global__ __launch_bounds__(256) void k1_proj(
    const float* __restrict__ h, const float* __restrict__ key_w,
    const float* __restrict__ erase_w, const float* __restrict__ add_w,
    const float* __restrict__ beta_w, const float* __restrict__ gate_w,
    const float* __restrict__ shift_w, float* __restrict__ raw) {
  __shared__ float hsT[32][34];
  __shared__ float wsT[32][34];
  const int t = threadIdx.x;
  const int b0 = blockIdx.x * 32;
  const int r0 = blockIdx.y * 32;
  const int kb = blockIdx.z * 512;
  const int tb = t & 15, tr = t >> 4;
  float acc00 = 0.f, acc01 = 0.f, acc10 = 0.f, acc11 = 0.f;
  for (int ko = 0; ko < 16; ++ko) {
    int kc = kb + ko * 32;
    __syncthreads();
    #pragma unroll
    for (int p = 0; p < 4; ++p) {
      int idx = t + p * 256;
      int col = idx & 31, row = idx >> 5;
      hsT[col][row] = h[(b0 + row) * HH + kc + col];
      int rg = r0 + row;
      float wv = 0.f;
      if (rg < 128)       wv = key_w[rg * HH + kc + col];
      else if (rg < 256)  wv = erase_w[(rg - 128) * HH + kc + col];
      else if (rg < 384)  wv = add_w[(rg - 256) * HH + kc + col];
      else if (rg == 384) wv = beta_w[kc + col];
      else if (rg == 385) wv = gate_w[kc + col];
      else if (rg < 389)  wv = shift_w[(rg - 386) * HH + kc + col];
      wsT[col][row] = wv;
    }
    __syncthreads();
    #pragma unroll
    for (int kk = 0; kk < 32; ++kk) {
      float a0 = hsT[kk][2 * tb], a1 = hsT[kk][2 * tb + 1];
      float w0 = wsT[kk][2 * tr], w1 = wsT[kk][2 * tr + 1];
      acc00 += a0 * w0; acc01 += a0 * w1;
      acc10 += a1 * w0; acc11 += a1 * w1;
    }
  }
  int bA = b0 + 2 * tb, bB = bA + 1;
  int rA = r0 + 2 * tr, rB = rA + 1;
  if (rA < 389) {
    unsafeAtomicAdd(&raw[bA * 392 + rA], acc00);
    unsafeAtomicAdd(&raw[bB * 392 + rA], acc10);
  }
  if (rB < 389) {
    unsafeAtomicAdd(&raw[bA * 392 + rB], acc01);
    unsafeAtomicAdd(&raw[bB * 392 + rB], acc11);
  }
}

// ---------------- K2: bias + activations + k-norm + s-softmax ----------------
__global__ __launch_bounds__(128) void k2_final(
    const float* __restrict__ raw, const float* __restrict__ key_b,
    const float* __restrict__ erase_b, const float* __restrict__ add_b,
    const float* __restrict__ beta_b, const float* __restrict__ gate_b,
    const float* __restrict__ shift_b,
    unsigned short* __restrict__ kbf, unsigned short* __restrict__ ebfT,
    unsigned short* __restrict__ abfT, float* __restrict__ beta,
    float* __restrict__ g, float* __restrict__ s3, float* __restrict__ knorm) {
  __shared__ float red[128];
  const int b = blockIdx.x, t = threadIdx.x;
  const float* rb = raw + b * 392;
  float kv = fminf(fmaxf(rb[t] + key_b[t], 0.f), 1.f);
  kbf[b * MM + t] = f2bf(kv);
  float ev = fminf(fmaxf(rb[128 + t] + erase_b[t], 0.f), 1.f);
  ebfT[t * BB + b] = f2bf(ev);
  float av = fminf(fmaxf(rb[256 + t] + add_b[t], 0.f), 1.f);
  abfT[t * BB + b] = f2bf(av);
  red[t] = kv * kv;
  __syncthreads();
  for (int off = 64; off >= 1; off >>= 1) {
    if (t < off) red[t] += red[t + off];
    __syncthreads();
  }
  if (t == 0) {
    knorm[b] = sqrtf(red[0]);
    beta[b] = fmaxf(rb[384] + beta_b[0], 0.f);
    g[b] = fminf(fmaxf(rb[385] + gate_b[0], 0.f), 1.f);
    float x0 = rb[386] + shift_b[0];
    float x1 = rb[387] + shift_b[1];
    float x2 = rb[388] + shift_b[2];
    float mx = fmaxf(x0, fmaxf(x1, x2));
    float e0 = __expf(x0 - mx), e1 = __expf(x1 - mx), e2 = __expf(x2 - mx);
    float inv = 1.f / (e0 + e1 + e2);
    s3[b * 3 + 0] = e0 * inv; s3[b * 3 + 1] = e1 * inv; s3[b * 3 + 2] = e2 * inv;
  }
}

// ---------------- K3: m row norms + m_bf16 + m_bf16^T (single m read) ----------------
__global__ __launch_bounds__(256) void k3_mprep(
    const float* __restrict__ m, unsigned short* __restrict__ mbf,
    unsigned short* __restrict__ mbfT, float* __restrict__ mnorm) {
  __shared__ float ldsT[128][65];
  const int t = threadIdx.x;
  const int n0 = blockIdx.x * 64;
  const int lane = t & 63, w = t >> 6;
  for (int ri = 0; ri < 16; ++ri) {
    int nloc = w * 16 + ri;
    int n = n0 + nloc;
    float v0 = m[n * MM + lane];
    float v1 = m[n * MM + lane + 64];
    mbf[n * MM + lane] = f2bf(v0);
    mbf[n * MM + lane + 64] = f2bf(v1);
    ldsT[lane][nloc] = v0;
    ldsT[lane + 64][nloc] = v1;
    float sq = v0 * v0 + v1 * v1;
    #pragma unroll
    for (int off = 32; off >= 1; off >>= 1) sq += __shfl_xor(sq, off, 64);
    if (lane == 0) mnorm[n] = sqrtf(sq);
  }
  __syncthreads();
  for (int q = 0; q < 32; ++q) {
    int mc = q * 4 + (t >> 6);
    int nloc = t & 63;
    mbfT[mc * NN + n0 + nloc] = f2bf(ldsT[mc][nloc]);
  }
}

// ---------------- K4: sim GEMM + fused exp (max=1 bound) + atomic rowsum ----
// cosine sim is bounded by ~1, so softmax can shift by 1.0 instead of rowmax:
// p = exp(beta*(sim-1)) stored bf16; rowsum accumulated via atomics.
__global__ __launch_bounds__(256) void k4_sim(
    const unsigned short* __restrict__ kbf, const unsigned short* __restrict__ mbf,
    const float* __restrict__ knorm, const float* __restrict__ mnorm,
    const float* __restrict__ beta, unsigned short* __restrict__ p,
    float* __restrict__ rowsum) {
  const int t = threadIdx.x;
  const int lane = t & 63, w = t >> 6;
  const int n0 = blockIdx.x * 64;
  const int b0 = blockIdx.y * 64 + w * 16;
  const int lm = lane & 15, quad = lane >> 4;
  floatx4 acc[4];
  #pragma unroll
  for (int i = 0; i < 4; ++i) acc[i] = (floatx4){0.f, 0.f, 0.f, 0.f};
  #pragma unroll
  for (int s = 0; s < 4; ++s) {
    short8 avf = *(const short8*)(kbf + (b0 + lm) * MM + s * 32 + quad * 8);
    #pragma unroll
    for (int nt = 0; nt < 4; ++nt) {
      short8 bvf = *(const short8*)(mbf + (n0 + nt * 16 + lm) * MM + s * 32 + quad * 8);
      acc[nt] = mfma16(avf, bvf, acc[nt]);
    }
  }
  float bt[4], kn[4], psum[4];
  #pragma unroll
  for (int r = 0; r < 4; ++r) {
    int b = b0 + quad * 4 + r;
    bt[r] = beta[b];
    kn[r] = knorm[b];
    psum[r] = 0.f;
  }
  #pragma unroll
  for (int nt = 0; nt < 4; ++nt) {
    int n = n0 + nt * 16 + lm;
    float mn = mnorm[n];
    #pragma unroll
    for (int r = 0; r < 4; ++r) {
      int b = b0 + quad * 4 + r;
      float val = acc[nt][r] / (kn[r] * mn + 1e-6f);
      float pe = __expf(bt[r] * (val - 1.f));
      p[(size_t)b * NN + n] = f2bf(pe);
      psum[r] += pe;
    }
  }
  #pragma unroll
  for (int r = 0; r < 4; ++r) {
    float s = psum[r];
    s += __shfl_xor(s, 1, 64);
    s += __shfl_xor(s, 2, 64);
    s += __shfl_xor(s, 4, 64);
    s += __shfl_xor(s, 8, 64);
    if (lm == 0) unsafeAtomicAdd(&rowsum[b0 + quad * 4 + r], s);
  }
}

// ---------------- KC: fused gate + 3-tap circular conv for 5 heads ----------
// Vectorized: 8 n per thread, 16B loads/stores, NO LDS / NO barriers.
// Conv halo (n-1, n+8) via 2 redundant scalar loads per head (L1-resident).
__global__ __launch_bounds__(256) void kc_update(
    const unsigned short* __restrict__ p, const float* __restrict__ ww,
    const float* __restrict__ wr, const float* __restrict__ gv,
    const float* __restrict__ s3, const float* __restrict__ rowsum,
    float* __restrict__ out_ww, float* __restrict__ out_wr) {
  const int b = blockIdx.x, t = threadIdx.x;
  const int n8 = blockIdx.y * 2048 + t * 8;
  const float g = gv[b];
  const float invZ = 1.f / rowsum[b];
  const float s0 = s3[b * 3], s1 = s3[b * 3 + 1], s2 = s3[b * 3 + 2];
  const float om = 1.f - g;
  const int nlo = (n8 - 1) & (NN - 1);
  const int nhi = (n8 + 8) & (NN - 1);
  const unsigned short* pb = p + (size_t)b * NN;
  // g * w_c for n in [n8-1, n8+8]
  const float gi = g * invZ;
  short8 pv8 = *(const short8*)(pb + n8);
  float wc[10];
  wc[0] = bf2f(pb[nlo]) * gi;
  #pragma unroll
  for (int j = 0; j < 8; ++j) wc[j + 1] = bf2f((unsigned short)pv8[j]) * gi;
  wc[9] = bf2f(pb[nhi]) * gi;
  #pragma unroll
  for (int h = 0; h < 5; ++h) {
    const float* pvh = (h == 0) ? (ww + (size_t)b * NN)
                                : (wr + ((size_t)(h - 1) * BB + b) * NN);
    float* poh = (h == 0) ? (out_ww + (size_t)b * NN)
                          : (out_wr + ((size_t)(h - 1) * BB + b) * NN);
    floatx4 a0 = *(const floatx4*)(pvh + n8);
    floatx4 a1 = *(const floatx4*)(pvh + n8 + 4);
    float wg[10];
    wg[0] = wc[0] + om * pvh[nlo];
    #pragma unroll
    for (int j = 0; j < 4; ++j) wg[j + 1] = wc[j + 1] + om * a0[j];
    #pragma unroll
    for (int j = 0; j < 4; ++j) wg[j + 5] = wc[j + 5] + om * a1[j];
    wg[9] = wc[9] + om * pvh[nhi];
    floatx4 o0, o1;
    #pragma unroll
    for (int j = 0; j < 4; ++j) o0[j] = s0 * wg[j + 2] + s1 * wg[j + 1] + s2 * wg[j];
    #pragma unroll
    for (int j = 0; j < 4; ++j) o1[j] = s0 * wg[j + 6] + s1 * wg[j + 5] + s2 * wg[j + 4];
    *(floatx4*)(poh + n8) = o0;
    *(floatx4*)(poh + n8 + 4) = o1;
  }
}

// ---------------- KD: m_t = m*(1 - ww^T e) + ww^T a ----------------
// Fuses the ww transpose: stages 64 b-rows x 64 n of fp32 ww per step into
// LDS as transposed bf16 (coalesced 256B-segment global reads), then MFMA.
__global__ __launch_bounds__(256) void kd_mem(
    const float* __restrict__ ww, const unsigned short* __restrict__ ebfT,
    const unsigned short* __restrict__ abfT, const float* __restrict__ m,
    float* __restrict__ out_m) {
  __shared__ unsigned short ldsw[64][66];  // [n_local][b_slice] bf16, padded
  const int t = threadIdx.x;
  const int lane = t & 63, w = t >> 6;
  const int lm = lane & 15, quad = lane >> 4;
  const int nb0 = blockIdx.x * 64;
  const int nb = nb0 + w * 16;
  const int row = t >> 2, c0 = (t & 3) * 16;  // staging: 64 rows x 64 cols
  floatx4 accE[8], accA[8];
  #pragma unroll
  for (int i = 0; i < 8; ++i) {
    accE[i] = (floatx4){0.f, 0.f, 0.f, 0.f};
    accA[i] = (floatx4){0.f, 0.f, 0.f, 0.f};
  }
  for (int s = 0; s < 8; ++s) {
    const float* wp = ww + (size_t)(s * 64 + row) * NN + nb0 + c0;
    floatx4 f0 = *(const floatx4*)(wp);
    floatx4 f1 = *(const floatx4*)(wp + 4);
    floatx4 f2 = *(const floatx4*)(wp + 8);
    floatx4 f3 = *(const floatx4*)(wp + 12);
    __syncthreads();  // previous iteration's LDS reads done
    #pragma unroll
    for (int j = 0; j < 4; ++j) {
      ldsw[c0 + j][row] = f2bf(f0[j]);
      ldsw[c0 + 4 + j][row] = f2bf(f1[j]);
      ldsw[c0 + 8 + j][row] = f2bf(f2[j]);
      ldsw[c0 + 12 + j][row] = f2bf(f3[j]);
    }
    __syncthreads();
    #pragma unroll
    for (int s2 = 0; s2 < 2; ++s2) {
      int k0 = s * 64 + s2 * 32 + quad * 8;
      short8 av = *(const short8*)(&ldsw[w * 16 + lm][s2 * 32 + quad * 8]);
      #pragma unroll
      for (int mt = 0; mt < 8; ++mt) {
        short8 evf = *(const short8*)(ebfT + (mt * 16 + lm) * BB + k0);
        short8 avf = *(const short8*)(abfT + (mt * 16 + lm) * BB + k0);
        accE[mt] = mfma16(av, evf, accE[mt]);
        accA[mt] = mfma16(av, avf, accA[mt]);
      }
    }
  }
  #pragma unroll
  for (int mt = 0; mt < 8; ++mt) {
    int mc = mt * 16 + lm;
    #pragma unroll
    for (int r = 0; r < 4; ++r) {
      int n = nb + quad * 4 + r;
      float mv = m[n * MM + mc];
      out_m[n * MM + mc] = mv * (1.f - accE[mt][r]) + accA[mt][r];
    }
  }
}

// ---------------- KE: r_t = einsum(wr, m) (bf16 MFMA, split-K=16 + atomics) ----------------
__global__ __launch_bounds__(256) void ke_read(
    const float* __restrict__ wr, const unsigned short* __restrict__ mbfT,
    float* __restrict__ out_r) {
  const int t = threadIdx.x;
  const int lane = t & 63, w = t >> 6;
  const int lm = lane & 15, quad = lane >> 4;
  const int rb0 = blockIdx.x * 64 + w * 16;
  const int kc0 = blockIdx.y * 1024;
  floatx4 acc[8];
  #pragma unroll
  for (int i = 0; i < 8; ++i) acc[i] = (floatx4){0.f, 0.f, 0.f, 0.f};
  for (int s = 0; s < 32; ++s) {
    int ns = kc0 + s * 32 + quad * 8;
    const float* ap = wr + (size_t)(rb0 + lm) * NN + ns;
    floatx4 f0 = *(const floatx4*)(ap);
    floatx4 f1 = *(const floatx4*)(ap + 4);
    short8 av;
    av[0] = (short)f2bf(f0[0]); av[1] = (short)f2bf(f0[1]);
    av[2] = (short)f2bf(f0[2]); av[3] = (short)f2bf(f0[3]);
    av[4] = (short)f2bf(f1[0]); av[5] = (short)f2bf(f1[1]);
    av[6] = (short)f2bf(f1[2]); av[7] = (short)f2bf(f1[3]);
    #pragma unroll
    for (int mt = 0; mt < 8; ++mt) {
      short8 bv = *(const short8*)(mbfT + (size_t)(mt * 16 + lm) * NN + ns);
      acc[mt] = mfma16(av, bv, acc[mt]);
    }
  }
  #pragma unroll
  for (int mt = 0; mt < 8; ++mt) {
    int mc = mt * 16 + lm;
    #pragma unroll
    for (int r = 0; r < 4; ++r) {
      int rb = rb0 + quad * 4 + r;
      int rr = rb >> 9, bb = rb & 511;
      unsafeAtomicAdd(&out_r[bb * (RR * MM) + rr * MM + mc], acc[mt][r]);
    }
  }
}

extern "C" void kernel_launch(void* const* d_in, const int* in_sizes, int n_in,
                              void* d_out, int out_size, void* d_ws, size_t ws_size,
                              hipStream_t stream) {
  const float* h_t    = (const float*)d_in[0];
  const float* wr     = (const float*)d_in[1];
  const float* ww     = (const float*)d_in[2];
  const float* m      = (const float*)d_in[3];
  const float* key_w  = (const float*)d_in[4];
  const float* key_b  = (const float*)d_in[5];
  const float* beta_w = (const float*)d_in[6];
  const float* beta_b = (const float*)d_in[7];
  const float* gate_w = (const float*)d_in[8];
  const float* gate_b = (const float*)d_in[9];
  const float* shift_w = (const float*)d_in[10];
  const float* shift_b = (const float*)d_in[11];
  const float* erase_w = (const float*)d_in[14];
  const float* erase_b = (const float*)d_in[15];
  const float* add_w   = (const float*)d_in[16];
  const float* add_b   = (const float*)d_in[17];

  char* wsb = (char*)d_ws;
  float* raw            = (float*)(wsb + 0);          // 512*392*4 = 802816
  float* rowsum         = (float*)(wsb + 802816);     // 2048 (memset with raw)
  unsigned short* kbf   = (unsigned short*)(wsb + 804864);   // 131072
  unsigned short* ebfT  = (unsigned short*)(wsb + 935936);   // 131072
  unsigned short* abfT  = (unsigned short*)(wsb + 1067008);  // 131072
  float* beta           = (float*)(wsb + 1198080);    // 2048
  float* g              = (float*)(wsb + 1200128);    // 2048
  float* s3             = (float*)(wsb + 1202176);    // 6144
  float* knorm          = (float*)(wsb + 1208320);    // 2048
  float* mnorm          = (float*)(wsb + 1210368);    // 65536
  unsigned short* mbf   = (unsigned short*)(wsb + 1275904);  // 4194304
  unsigned short* mbfT  = (unsigned short*)(wsb + 5470208);  // 4194304
  unsigned short* pbuf  = (unsigned short*)(wsb + 9664512);  // 16777216 (total ~26.4 MB)

  float* out_r  = (float*)d_out;                 // (B,R,M)  262144
  float* out_wr = (float*)d_out + 262144;        // (R,B,N)  33554432
  float* out_ww = (float*)d_out + 33816576;      // (B,N)    8388608
  float* out_m  = (float*)d_out + 42205184;      // (N,M)    2097152

  hipMemsetAsync(d_out, 0, 262144 * sizeof(float), stream);   // r_t accum
  hipMemsetAsync(raw, 0, 804864, stream);                     // raw + rowsum

  k1_proj<<<dim3(16, 13, 2), 256, 0, stream>>>(h_t, key_w, erase_w, add_w,
                                               beta_w, gate_w, shift_w, raw);
  k2_final<<<512, 128, 0, stream>>>(raw, key_b, erase_b, add_b, beta_b, gate_b,
                                    shift_b, kbf, ebfT, abfT, beta, g, s3, knorm);
  k3_mprep<<<256, 256, 0, stream>>>(m, mbf, mbfT, mnorm);
  k4_sim<<<dim3(256, 8), 256, 0, stream>>>(kbf, mbf, knorm, mnorm, beta, pbuf, rowsum);
  kc_update<<<dim3(512, 8), 256, 0, stream>>>(pbuf, ww, wr, g, s3, rowsum,
                                              out_ww, out_wr);
  kd_mem<<<256, 256, 0, stream>>>(ww, ebfT, abfT, m, out_m);
  ke_read<<<dim3(32, 16), 256, 0, stream>>>(wr, mbfT, out_r);
}